// Round 2
// baseline (329.971 us; speedup 1.0000x reference)
//
#include <hip/hip_runtime.h>

typedef _Float16 f16;
typedef _Float16 f16x8 __attribute__((ext_vector_type(8)));
typedef _Float16 f16x4 __attribute__((ext_vector_type(4)));
typedef float    f32x4 __attribute__((ext_vector_type(4)));

#define MFMA16(a, b, c) __builtin_amdgcn_mfma_f32_16x16x32_f16((a), (b), (c), 0, 0, 0)

constexpr int T = 64;    // sequence length
constexpr int C = 384;   // n_embd
constexpr int H = 64;    // head size
constexpr float SCALE = 3.26598632371090f;  // 64 * 384^-0.5

// ---------------------------------------------------------------------------
// Pack Wk,Wq,Wv (fp32 [64][384]) into f16 MFMA-fragment order in d_ws.
// R6 layout is kt-major so one wave's 12 combo-frags for a given kt are
// contiguous (12 KB slice, L1/L2-resident):
//   tile2 = kt*12 + wi*4 + ht      (wi: 0=K,1=Q,2=V)
//   Wp[tile2*512 + lane*8 + j] = W_wi[16*ht + (lane&15)][32*kt + 8*(lane>>4) + j]
// ---------------------------------------------------------------------------
__global__ void pack_w(const float* __restrict__ Wk, const float* __restrict__ Wq,
                       const float* __restrict__ Wv, f16* __restrict__ Wp) {
  int tid = blockIdx.x * blockDim.x + threadIdx.x;
  if (tid >= 3 * 12 * 4 * 64) return;
  int lane = tid & 63;
  int tile = tid >> 6;          // (wi*12 + kt)*4 + ht   (decode as before)
  int ht = tile & 3;
  int kt = (tile >> 2) % 12;
  int wi = tile / 48;
  const float* W = (wi == 0) ? Wk : ((wi == 1) ? Wq : Wv);
  int h = 16 * ht + (lane & 15);
  int c = 32 * kt + 8 * (lane >> 4);
  const float* src = W + h * C + c;
  f16x8 v;
#pragma unroll
  for (int j = 0; j < 8; ++j) v[j] = (f16)src[j];
  int tile2 = kt * 12 + wi * 4 + ht;   // kt-major store
  *(f16x8*)(Wp + (size_t)tile2 * 512 + lane * 8) = v;
}

// ---------------------------------------------------------------------------
// Fused head kernel: one block per batch, 4 waves.
// R6: barrier-free phase 1. Ownership inverted vs R5: wave w owns row-tile
// tt=w and ALL 12 W-combos (acc[12]). The x-fragment a wave needs is exactly
// the 16 rows it addresses itself, so x is loaded global->VGPR directly
// (identical addresses/coalescing to the old DMA path) and converted in
// registers. No LDS staging, no global_load_lds, ZERO phase-1 barriers:
// each wave self-paces on its own register-dependency vmcnts (compiler-
// precise). Wp is read per-wave (4x/block redundancy) but is 144 KB,
// fully L2-resident, and the 12 KB per-kt slice is shared through L1 by the
// block's in-phase waves.
// Phase-1 epilogue writes q/k/vT to LDS (wave-private rows/cols), ONE
// __syncthreads, then phases 2-4 unchanged from R3.
// ---------------------------------------------------------------------------
__global__ __launch_bounds__(256, 3) void head_fused(
    const float* __restrict__ x, const f16* __restrict__ Wp,
    float* __restrict__ out) {
  // pitch 72 f16 = 36 dwords; 36 % 32 = 4 -> <=2-way LDS bank aliasing (free)
  __shared__ f16 qp_lds[64][72];  // phases 1-2: q[t][h]; phases 3-4: P[t][s]
  __shared__ f16 k_lds[64][72];   // k[t][h]
  __shared__ f16 vT_lds[64][72];  // v^T[h][t]

  const int b = blockIdx.x;
  const int tid = threadIdx.x;
  const int w = tid >> 6;       // wave 0..3 == row-tile tt
  const int lane = tid & 63;
  const int l15 = lane & 15;
  const int g = lane >> 4;      // quad 0..3
  const int t_ = 16 * w + l15;  // this lane's t for phases 2-4

  const f32x4 vzero = {0.0f, 0.0f, 0.0f, 0.0f};
  f32x4 acc[12];                // combo cb = 4m+ht, m: 0=K,1=Q,2=V
#pragma unroll
  for (int cb = 0; cb < 12; ++cb) acc[cb] = vzero;

  // x fragment source: row 16w+l15, col 8g (+32 per kt). Same addresses the
  // old DMA used -> identical HBM coalescing (16 rows x 128 B per wave-kt).
  const float* gsrc = x + (size_t)b * T * C + (size_t)(16 * w + l15) * C + 8 * g;
  const f16* wsrc = Wp + lane * 8;

  // ---- Phase 1: 12 k-chunks, barrier-free, depth-1 register prefetch on x
  f32x4 A0 = *(const f32x4*)(gsrc + 0);
  f32x4 A1 = *(const f32x4*)(gsrc + 4);
#pragma unroll 2
  for (int kt = 0; kt < 12; ++kt) {
    f32x4 B0, B1;
    if (kt + 1 < 12) {
      B0 = *(const f32x4*)(gsrc + (kt + 1) * 32 + 0);
      B1 = *(const f32x4*)(gsrc + (kt + 1) * 32 + 4);
    }
    f16x8 wf[12];
#pragma unroll
    for (int cb = 0; cb < 12; ++cb)
      wf[cb] = *(const f16x8*)(wsrc + ((size_t)kt * 12 + cb) * 512);
    f16x8 xf;
#pragma unroll
    for (int j = 0; j < 4; ++j) { xf[j] = (f16)A0[j]; xf[4 + j] = (f16)A1[j]; }
#pragma unroll
    for (int cb = 0; cb < 8; ++cb)   // K,Q: D[h][t] (W as A, x as B)
      acc[cb] = MFMA16(wf[cb], xf, acc[cb]);
#pragma unroll
    for (int cb = 8; cb < 12; ++cb)  // V: D[t][h] (x as A, W as B)
      acc[cb] = MFMA16(xf, wf[cb], acc[cb]);
    A0 = B0; A1 = B1;
  }

  // ---- Phase-1 epilogue: write q/k/vT to LDS, D-layout, b64 per tile.
  // K/Q: rows 16w+l15 (wave-private). V: byte-disjoint columns 16w+4g.
#pragma unroll
  for (int cb = 0; cb < 12; ++cb) {
    int m = cb >> 2;
    int ht = cb & 3;
    f16x4 pd;
#pragma unroll
    for (int r = 0; r < 4; ++r) pd[r] = (f16)acc[cb][r];
    if (m == 0) {        // K: col=t (16w+l15), row=h (16ht+4g+r)
      *(f16x4*)&k_lds[16 * w + l15][16 * ht + 4 * g] = pd;
    } else if (m == 1) { // Q
      *(f16x4*)&qp_lds[16 * w + l15][16 * ht + 4 * g] = pd;
    } else {             // V: col=h (16ht+l15), row=t (16w+4g+r)
      *(f16x4*)&vT_lds[16 * ht + l15][16 * w + 4 * g] = pd;
    }
  }
  __syncthreads();  // the only block-wide barrier in the kernel

  // ---- Phase 2: S^T = k.q^T  (lane holds column t_ of S, 16 s-entries)
  f32x4 accs[4];
#pragma unroll
  for (int i = 0; i < 4; ++i) accs[i] = vzero;
#pragma unroll
  for (int kt = 0; kt < 2; ++kt) {
    f16x8 qf = *(const f16x8*)&qp_lds[t_][32 * kt + 8 * g];
#pragma unroll
    for (int mt = 0; mt < 4; ++mt) {
      f16x8 kf = *(const f16x8*)&k_lds[16 * mt + l15][32 * kt + 8 * g];
      accs[mt] = MFMA16(kf, qf, accs[mt]);  // D[s][t]: s = 16mt+4g+r, t = t_
    }
  }

  // ---- Phase 3: causal mask + softmax over s (per column t_, fp32)
  float e[16];
  float mx = -__builtin_inff();
#pragma unroll
  for (int mt = 0; mt < 4; ++mt) {
#pragma unroll
    for (int r = 0; r < 4; ++r) {
      int s = 16 * mt + 4 * g + r;
      float lv = accs[mt][r] * SCALE;
      lv = (s <= t_) ? lv : -__builtin_inff();
      e[mt * 4 + r] = lv;
      mx = fmaxf(mx, lv);
    }
  }
  mx = fmaxf(mx, __shfl_xor(mx, 16));
  mx = fmaxf(mx, __shfl_xor(mx, 32));
  float sm = 0.0f;
#pragma unroll
  for (int i = 0; i < 16; ++i) { e[i] = __expf(e[i] - mx); sm += e[i]; }
  sm += __shfl_xor(sm, 16);
  sm += __shfl_xor(sm, 32);
  const float inv = 1.0f / sm;
  // P overwrites qp_lds rows [16w,16w+16): wave-private rows; all other
  // waves' post-barrier qp_lds reads are own-row only. No barrier needed.
#pragma unroll
  for (int mt = 0; mt < 4; ++mt) {
    f16x4 pp;
#pragma unroll
    for (int r = 0; r < 4; ++r) pp[r] = (f16)(e[mt * 4 + r] * inv);
    *(f16x4*)&qp_lds[t_][16 * mt + 4 * g] = pp;  // P[t][s], s = 16mt+4g+r
  }

  // ---- Phase 4: out^T = v^T . P^T  (A = vT, B-frag from P[t][s])
  f32x4 acco[4];
#pragma unroll
  for (int i = 0; i < 4; ++i) acco[i] = vzero;
#pragma unroll
  for (int kt = 0; kt < 2; ++kt) {
    f16x8 pf = *(const f16x8*)&qp_lds[t_][32 * kt + 8 * g];
#pragma unroll
    for (int mt = 0; mt < 4; ++mt) {
      f16x8 vf = *(const f16x8*)&vT_lds[16 * mt + l15][32 * kt + 8 * g];
      acco[mt] = MFMA16(vf, pf, acco[mt]);  // D[h][t]: h = 16mt+4g+r, t = t_
    }
  }

  // ---- store: out[b][t][h] fp32, 4 consecutive h per reg quad -> float4
  float* orow = out + ((size_t)b * T + t_) * H;
#pragma unroll
  for (int mt = 0; mt < 4; ++mt) {
    *(f32x4*)(orow + 16 * mt + 4 * g) = acco[mt];
  }
}

extern "C" void kernel_launch(void* const* d_in, const int* in_sizes, int n_in,
                              void* d_out, int out_size, void* d_ws, size_t ws_size,
                              hipStream_t stream) {
  const float* x  = (const float*)d_in[0];
  const float* Wk = (const float*)d_in[1];
  const float* Wq = (const float*)d_in[2];
  const float* Wv = (const float*)d_in[3];
  float* out = (float*)d_out;
  f16* Wp = (f16*)d_ws;  // 3*12*4*64*8 f16 = 147456 B

  // Re-pack every launch: d_ws is re-poisoned before each timed call.
  pack_w<<<36, 256, 0, stream>>>(Wk, Wq, Wv, Wp);
  head_fused<<<2048, 256, 0, stream>>>(x, Wp, out);
}